// Round 10
// baseline (304.744 us; speedup 1.0000x reference)
//
#include <hip/hip_runtime.h>
#include <cstdint>
#include <cstddef>

typedef float  f32x4  __attribute__((ext_vector_type(4)));
typedef short  bf16x8 __attribute__((ext_vector_type(8)));

constexpr int Bc = 4, Lc = 1024, Dc = 1024, Kc = 8, Hc = 64, NHc = 512;
constexpr float SCALE = 0.125f;                       // 1/sqrt(64)
constexpr long long GSZ = 2LL * Bc * Kc * Lc * Lc;    // graphs elems (both layers)
constexpr long long OSZ = (long long)Bc * Lc * Dc;    // hidden elems per layer
constexpr int QB = 16;                                // q-rows per attn block

__device__ __forceinline__ unsigned short f2bf(float f) {
    unsigned u = __float_as_uint(f);
    u += 0x7fffu + ((u >> 16) & 1u);   // RNE
    return (unsigned short)(u >> 16);
}
__device__ __forceinline__ float bf2f(unsigned short s) {
    return __uint_as_float((unsigned)s << 16);
}

// ---------------------------------------------------------------------------
// cast fp32 -> bf16, 8 elems/thread
// ---------------------------------------------------------------------------
__global__ __launch_bounds__(256)
void cast_bf16(const float* __restrict__ in, unsigned short* __restrict__ outp, int n)
{
    const int i = (blockIdx.x * 256 + threadIdx.x) * 8;
    if (i >= n) return;
    float4 a = *(const float4*)(in + i);
    float4 b = *(const float4*)(in + i + 4);
    bf16x8 v;
    v[0] = (short)f2bf(a.x); v[1] = (short)f2bf(a.y);
    v[2] = (short)f2bf(a.z); v[3] = (short)f2bf(a.w);
    v[4] = (short)f2bf(b.x); v[5] = (short)f2bf(b.y);
    v[6] = (short)f2bf(b.z); v[7] = (short)f2bf(b.w);
    *(bf16x8*)(outp + i) = v;
}

// ---------------------------------------------------------------------------
// cast + transpose: src fp32 [4][1024 s][1024 d] -> hidT bf16 [4][1024 d][1024 s]
// 64x64 tile via LDS.  (verified correct in round 6)
// ---------------------------------------------------------------------------
__global__ __launch_bounds__(256)
void cast_tr(const float* __restrict__ src, unsigned short* __restrict__ hidT)
{
    __shared__ float Tl[64][68];
    const int b = blockIdx.z, s0 = blockIdx.x * 64, d0 = blockIdx.y * 64;
    const int t = threadIdx.x;
    {
        const int r = t >> 4, c = (t & 15) * 4;
        #pragma unroll
        for (int i = 0; i < 4; ++i)
            *(float4*)&Tl[r + 16 * i][c] =
                *(const float4*)&src[((size_t)(b * Lc + s0 + r + 16 * i)) * Dc + d0 + c];
    }
    __syncthreads();
    {
        const int d = t >> 2, sc = (t & 3) * 16;
        bf16x8 v0, v1;
        #pragma unroll
        for (int j = 0; j < 8; ++j) v0[j] = (short)f2bf(Tl[sc + j][d]);
        #pragma unroll
        for (int j = 0; j < 8; ++j) v1[j] = (short)f2bf(Tl[sc + 8 + j][d]);
        unsigned short* dp = hidT + ((size_t)(b * Dc + d0 + d)) * Lc + s0 + sc;
        *(bf16x8*)dp       = v0;
        *(bf16x8*)(dp + 8) = v1;
    }
}

// ---------------------------------------------------------------------------
// K0: W [1024 k][512 n] fp32 -> Wt [512 n][1024 k] bf16, parked in d_out att
// region (overwritten later by attn_fused). z: layer*2 + (0=q,1=k).
// ---------------------------------------------------------------------------
__global__ __launch_bounds__(256)
void wtrans(const float* __restrict__ Wq, const float* __restrict__ Wk,
            float* __restrict__ outbase)
{
    __shared__ float Tl[64][68];
    const int z = blockIdx.z, layer = z >> 1, m = z & 1;
    const float* src = (m ? Wk : Wq) + (size_t)layer * Dc * NHc;
    unsigned short* dst = (unsigned short*)(outbase + (size_t)layer * (GSZ / 2))
                          + (size_t)m * NHc * Dc;
    const int k0 = blockIdx.x * 64, n0 = blockIdx.y * 64;
    const int t = threadIdx.x;
    {
        const int r0 = t >> 4, c0 = (t & 15) * 4;
        #pragma unroll
        for (int i = 0; i < 4; ++i)
            *(float4*)&Tl[r0 + 16 * i][c0] =
                *(const float4*)&src[(size_t)(k0 + r0 + 16 * i) * NHc + n0 + c0];
    }
    __syncthreads();
    {
        const int nn = t >> 2, ks = (t & 3) * 16;
        bf16x8 v0, v1;
        #pragma unroll
        for (int j = 0; j < 8; ++j) v0[j] = (short)f2bf(Tl[ks + j][nn]);
        #pragma unroll
        for (int j = 0; j < 8; ++j) v1[j] = (short)f2bf(Tl[ks + 8 + j][nn]);
        unsigned short* dp = dst + (size_t)(n0 + nn) * Dc + k0 + ks;
        *(bf16x8*)dp       = v0;
        *(bf16x8*)(dp + 8) = v1;
    }
}

// ---------------------------------------------------------------------------
// K1: q/k projection GEMM, LDS-staged (coalesced global reads), double-buffered.
// Tile 128x128, BK=32, 512 thr = 8 waves, wave tile 64x32 (4x2 frags).
// ---------------------------------------------------------------------------
__global__ __launch_bounds__(512)
void qk_gemm(const unsigned short* __restrict__ hidb,
             const unsigned short* __restrict__ Wtq, const unsigned short* __restrict__ Wtk,
             const float* __restrict__ bq, const float* __restrict__ bk,
             unsigned short* __restrict__ qbuf, unsigned short* __restrict__ kbuf)
{
    __shared__ unsigned short As[2][128][40];
    __shared__ unsigned short Bs[2][128][40];

    const unsigned short* Wt = blockIdx.z ? Wtk : Wtq;
    const float* bi = blockIdx.z ? bk : bq;
    unsigned short* C = blockIdx.z ? kbuf : qbuf;
    const int m0 = blockIdx.x * 128, n0 = blockIdx.y * 128;
    const int t = threadIdx.x, lane = t & 63, w = t >> 6;
    const int lr = lane & 15, lg = lane >> 4;
    const int wmloc = (w >> 2) * 64, wnloc = (w & 3) * 32;

    const int srow = t >> 2, scol = (t & 3) * 8;
    const unsigned short* Ag = hidb + (size_t)(m0 + srow) * Dc + scol;
    const unsigned short* Bg = Wt   + (size_t)(n0 + srow) * Dc + scol;

    f32x4 acc[4][2] = {};
    bf16x8 ra = *(const bf16x8*)Ag;
    bf16x8 rb = *(const bf16x8*)Bg;

    for (int it = 0; it < 32; ++it) {
        const int buf = it & 1;
        *(bf16x8*)&As[buf][srow][scol] = ra;
        *(bf16x8*)&Bs[buf][srow][scol] = rb;
        __syncthreads();
        if (it < 31) {
            ra = *(const bf16x8*)(Ag + (it + 1) * 32);
            rb = *(const bf16x8*)(Bg + (it + 1) * 32);
        }
        bf16x8 a[4], bfr[2];
        #pragma unroll
        for (int mi = 0; mi < 4; ++mi)
            a[mi] = *(const bf16x8*)&As[buf][wmloc + mi * 16 + lr][lg * 8];
        #pragma unroll
        for (int ni = 0; ni < 2; ++ni)
            bfr[ni] = *(const bf16x8*)&Bs[buf][wnloc + ni * 16 + lr][lg * 8];
        #pragma unroll
        for (int mi = 0; mi < 4; ++mi)
            #pragma unroll
            for (int ni = 0; ni < 2; ++ni)
                acc[mi][ni] = __builtin_amdgcn_mfma_f32_16x16x32_bf16(a[mi], bfr[ni], acc[mi][ni], 0, 0, 0);
    }

    #pragma unroll
    for (int ni = 0; ni < 2; ++ni) {
        const int gc = n0 + wnloc + ni * 16 + lr;
        const float bv = bi[gc];
        #pragma unroll
        for (int mi = 0; mi < 4; ++mi)
            #pragma unroll
            for (int r = 0; r < 4; ++r) {
                const int row = m0 + wmloc + mi * 16 + lg * 4 + r;
                float v = fmaxf(acc[mi][ni][r] + bv, 0.0f);
                C[(size_t)row * NHc + gc] = f2bf(v);
            }
    }
}

// ---------------------------------------------------------------------------
// K2 (fused): scores -> softmax -> att write -> PV -> residual, QB=16 q-rows
// per block, 512 thr = 8 waves.  All MFMA operand reads are b128 from LDS:
// P1 stages 4 K-chunks per barrier-pair (2 waves/chunk); P3 stages V-tiles
// from pre-transposed hidT (coalesced) into VT and reads rows contiguously.
// 67 KB LDS -> 2 blocks/CU.  Causal: valid iff s < q; row 0 -> uniform 1/1024.
// ---------------------------------------------------------------------------
__global__ __launch_bounds__(512)
void attn_fused(const unsigned short* __restrict__ qbuf,
                const unsigned short* __restrict__ kbuf,
                const unsigned short* __restrict__ hidT,
                const float* __restrict__ res,
                float* __restrict__ att, float* __restrict__ outp,
                unsigned short* __restrict__ hidnext)
{
    __shared__ unsigned short Sb[QB][1040];     // bf16 score/P strip (33.3 KB)
    __shared__ unsigned short KS[4][64][66];    // K staging (33.8 KB), aliased:
    unsigned short (*VT)[128][66] = (unsigned short (*)[128][66])KS;  // V staging

    const int id = blockIdx.x;
    const int kh = id & 7, qt = (id >> 3) & 63, b = id >> 9;
    const int q0 = qt * QB;
    const int t = threadIdx.x, lane = t & 63, w = t >> 6;
    const int lr = lane & 15, lg = lane >> 4;

    bf16x8 aq[2];
    #pragma unroll
    for (int ks = 0; ks < 2; ++ks)
        aq[ks] = *(const bf16x8*)(qbuf + (size_t)(b * Lc + q0 + lr) * NHc + kh * Hc + ks * 32 + lg * 8);

    const int ccount = (q0 + QB + 63) >> 6;   // 64-col chunks needed (1..16)

    // ---- P1: scores -> Sb (bf16).  4 K-chunks per barrier-pair. ----
    const int ch = t >> 7, krow = (t & 127) >> 1, kcol = (t & 1) * 32;
    for (int cb = 0; cb < ccount; cb += 4) {
        const int cs = cb + ch;
        if (cs < ccount) {
            const unsigned short* kp = kbuf + (size_t)(b * Lc + cs * 64 + krow) * NHc + kh * Hc + kcol;
            *(bf16x8*)&KS[ch][krow][kcol]      = *(const bf16x8*)kp;
            *(bf16x8*)&KS[ch][krow][kcol + 8]  = *(const bf16x8*)(kp + 8);
            *(bf16x8*)&KS[ch][krow][kcol + 16] = *(const bf16x8*)(kp + 16);
            *(bf16x8*)&KS[ch][krow][kcol + 24] = *(const bf16x8*)(kp + 24);
        }
        __syncthreads();
        const int c = cb + (w >> 1);
        if (c < ccount) {
            f32x4 acc[2] = {};
            #pragma unroll
            for (int ks = 0; ks < 2; ++ks)
                #pragma unroll
                for (int i = 0; i < 2; ++i) {
                    const int ni = (w & 1) * 2 + i;
                    bf16x8 bfr = *(const bf16x8*)&KS[w >> 1][ni * 16 + lr][ks * 32 + lg * 8];
                    acc[i] = __builtin_amdgcn_mfma_f32_16x16x32_bf16(aq[ks], bfr, acc[i], 0, 0, 0);
                }
            #pragma unroll
            for (int i = 0; i < 2; ++i) {
                const int ni = (w & 1) * 2 + i;
                #pragma unroll
                for (int r = 0; r < 4; ++r)
                    Sb[lg * 4 + r][c * 64 + ni * 16 + lr] = f2bf(acc[i][r] * SCALE);
            }
        }
        __syncthreads();
    }

    // ---- P2: softmax, 2 rows per wave.  fp32 att to global; bf16 P to Sb. ----
    #pragma unroll
    for (int i = 0; i < 2; ++i) {
        const int row = w * 2 + i, qrow = q0 + row;
        float* orow = att + ((size_t)(b * Kc + kh) * Lc + qrow) * Lc;
        if (qrow == 0) {
            const float u = 1.0f / 1024.0f;
            const short ub = (short)f2bf(u);
            bf16x8 pv8;
            #pragma unroll
            for (int j = 0; j < 8; ++j) pv8[j] = ub;
            #pragma unroll
            for (int tt = 0; tt < 2; ++tt) {
                const int col = lane * 8 + tt * 512;
                float4 o = { u, u, u, u };
                *(float4*)(orow + col) = o;
                *(float4*)(orow + col + 4) = o;
                *(bf16x8*)&Sb[row][col] = pv8;
            }
            continue;
        }
        float p[16];
        float mx = -3.0e38f;
        #pragma unroll
        for (int tt = 0; tt < 2; ++tt) {
            const int col = lane * 8 + tt * 512;
            bf16x8 v = *(const bf16x8*)&Sb[row][col];
            #pragma unroll
            for (int j = 0; j < 8; ++j) {
                const float f = bf2f((unsigned short)v[j]);
                p[tt * 8 + j] = f;
                if (col + j < qrow) mx = fmaxf(mx, f);
            }
        }
        #pragma unroll
        for (int off = 1; off < 64; off <<= 1) mx = fmaxf(mx, __shfl_xor(mx, off));
        float sum = 0.0f;
        #pragma unroll
        for (int tt = 0; tt < 2; ++tt)
            #pragma unroll
            for (int j = 0; j < 8; ++j) {
                const int col = lane * 8 + tt * 512 + j;
                const float e = (col < qrow) ? __expf(p[tt * 8 + j] - mx) : 0.0f;
                p[tt * 8 + j] = e; sum += e;
            }
        #pragma unroll
        for (int off = 1; off < 64; off <<= 1) sum += __shfl_xor(sum, off);
        const float inv = 1.0f / sum;
        #pragma unroll
        for (int tt = 0; tt < 2; ++tt) {
            const int col = lane * 8 + tt * 512;
            float4 o0 = { p[tt*8+0]*inv, p[tt*8+1]*inv, p[tt*8+2]*inv, p[tt*8+3]*inv };
            float4 o1 = { p[tt*8+4]*inv, p[tt*8+5]*inv, p[tt*8+6]*inv, p[tt*8+7]*inv };
            *(float4*)(orow + col) = o0;
            *(float4*)(orow + col + 4) = o1;
            bf16x8 pb;
            #pragma unroll
            for (int j = 0; j < 8; ++j) pb[j] = (short)f2bf(p[tt * 8 + j] * inv);
            *(bf16x8*)&Sb[row][col] = pb;
        }
    }
    __syncthreads();

    // ---- P3: PV (+residual).  V from hidT, staged coalesced, b128 reads. ----
    const int stiles = (qt == 0) ? 16 : ccount;   // row 0 is a full uniform row
    f32x4 acc3 = {};
    const int dloc = w * 16 + lr, dcol = kh * 128 + dloc;
    const int vd = t >> 2, vsc = (t & 3) * 16;
    const unsigned short* vbase = hidT + (size_t)(b * Dc + kh * 128 + vd) * Lc + vsc;
    for (int ti = 0; ti < stiles; ++ti) {
        const int buf = ti & 1;
        const unsigned short* vp = vbase + ti * 64;
        *(bf16x8*)&VT[buf][vd][vsc]     = *(const bf16x8*)vp;
        *(bf16x8*)&VT[buf][vd][vsc + 8] = *(const bf16x8*)(vp + 8);
        __syncthreads();
        #pragma unroll
        for (int ks = 0; ks < 2; ++ks) {
            bf16x8 pa = *(const bf16x8*)&Sb[lr][ti * 64 + ks * 32 + lg * 8];
            bf16x8 bb = *(const bf16x8*)&VT[buf][dloc][ks * 32 + lg * 8];
            acc3 = __builtin_amdgcn_mfma_f32_16x16x32_bf16(pa, bb, acc3, 0, 0, 0);
        }
    }

    #pragma unroll
    for (int r = 0; r < 4; ++r) {
        const size_t idx = (size_t)(b * Lc + q0 + lg * 4 + r) * Dc + dcol;
        const float v = res[idx] + acc3[r];
        outp[idx] = v;
        if (hidnext) hidnext[idx] = f2bf(v);
    }
}

// ---------------------------------------------------------------------------
extern "C" void kernel_launch(void* const* d_in, const int* in_sizes, int n_in,
                              void* d_out, int out_size, void* d_ws, size_t ws_size,
                              hipStream_t stream)
{
    const float* x  = (const float*)d_in[0];
    const float* Wq = (const float*)d_in[1];
    const float* bq = (const float*)d_in[2];
    const float* Wk = (const float*)d_in[3];
    const float* bk = (const float*)d_in[4];
    float* out = (float*)d_out;

    unsigned short* hidb = (unsigned short*)d_ws;              // [4096][1024] bf16 (8 MB)
    unsigned short* hidT = hidb + (size_t)Bc * Lc * Dc;        // [4][1024 d][1024 s] (8 MB)
    unsigned short* qb   = hidT + (size_t)Bc * Dc * Lc;        // [4096][512]  bf16 (4 MB)
    unsigned short* kb   = qb   + (size_t)Bc * Lc * NHc;       // [4096][512]  bf16 (4 MB)

    const int nhid = Bc * Lc * Dc;   // 4194304

    cast_bf16<<<nhid / 8 / 256, 256, 0, stream>>>(x, hidb, nhid);
    wtrans<<<dim3(16, 8, 4), 256, 0, stream>>>(Wq, Wk, out);

    for (int l = 0; l < 2; ++l) {
        float* attL = out + (size_t)l * (GSZ / 2);
        float* outL = out + GSZ + (size_t)l * OSZ;
        const float* resL = l ? (out + GSZ) : x;
        const float* srcL = l ? (out + GSZ) : x;   // fp32 hidden entering layer l
        const unsigned short* WtL = (const unsigned short*)attL;

        cast_tr<<<dim3(16, 16, 4), 256, 0, stream>>>(srcL, hidT);

        qk_gemm<<<dim3(32, 4, 2), 512, 0, stream>>>(
            hidb, WtL, WtL + (size_t)NHc * Dc, bq + l * NHc, bk + l * NHc, qb, kb);

        attn_fused<<<Bc * 64 * Kc, 512, 0, stream>>>(
            qb, kb, hidT, resL, attL, outL, l == 0 ? hidb : (unsigned short*)nullptr);
    }
}

// Round 11
// 196.312 us; speedup vs baseline: 1.5523x; 1.5523x over previous
//
#include <hip/hip_runtime.h>
#include <cstdint>
#include <cstddef>

typedef float  f32x4  __attribute__((ext_vector_type(4)));
typedef short  bf16x8 __attribute__((ext_vector_type(8)));

constexpr int Bc = 4, Lc = 1024, Dc = 1024, Kc = 8, Hc = 64, NHc = 512;
constexpr float SCALE = 0.125f;                       // 1/sqrt(64)
constexpr long long GSZ = 2LL * Bc * Kc * Lc * Lc;    // graphs elems (both layers)
constexpr long long OSZ = (long long)Bc * Lc * Dc;    // hidden elems per layer
constexpr int QB = 16;                                // q-rows per attn block

__device__ __forceinline__ unsigned short f2bf(float f) {
    unsigned u = __float_as_uint(f);
    u += 0x7fffu + ((u >> 16) & 1u);   // RNE
    return (unsigned short)(u >> 16);
}
__device__ __forceinline__ float bf2f(unsigned short s) {
    return __uint_as_float((unsigned)s << 16);
}

// ---------------------------------------------------------------------------
// cast fp32 -> bf16, 8 elems/thread
// ---------------------------------------------------------------------------
__global__ __launch_bounds__(256)
void cast_bf16(const float* __restrict__ in, unsigned short* __restrict__ outp, int n)
{
    const int i = (blockIdx.x * 256 + threadIdx.x) * 8;
    if (i >= n) return;
    float4 a = *(const float4*)(in + i);
    float4 b = *(const float4*)(in + i + 4);
    bf16x8 v;
    v[0] = (short)f2bf(a.x); v[1] = (short)f2bf(a.y);
    v[2] = (short)f2bf(a.z); v[3] = (short)f2bf(a.w);
    v[4] = (short)f2bf(b.x); v[5] = (short)f2bf(b.y);
    v[6] = (short)f2bf(b.z); v[7] = (short)f2bf(b.w);
    *(bf16x8*)(outp + i) = v;
}

// ---------------------------------------------------------------------------
// K0: W [1024 k][512 n] fp32 -> Wt [512 n][1024 k] bf16, parked in d_out att
// region (overwritten later by attn_fused). z: layer*2 + (0=q,1=k).
// ---------------------------------------------------------------------------
__global__ __launch_bounds__(256)
void wtrans(const float* __restrict__ Wq, const float* __restrict__ Wk,
            float* __restrict__ outbase)
{
    __shared__ float Tl[64][68];
    const int z = blockIdx.z, layer = z >> 1, m = z & 1;
    const float* src = (m ? Wk : Wq) + (size_t)layer * Dc * NHc;
    unsigned short* dst = (unsigned short*)(outbase + (size_t)layer * (GSZ / 2))
                          + (size_t)m * NHc * Dc;
    const int k0 = blockIdx.x * 64, n0 = blockIdx.y * 64;
    const int t = threadIdx.x;
    {
        const int r0 = t >> 4, c0 = (t & 15) * 4;
        #pragma unroll
        for (int i = 0; i < 4; ++i)
            *(float4*)&Tl[r0 + 16 * i][c0] =
                *(const float4*)&src[(size_t)(k0 + r0 + 16 * i) * NHc + n0 + c0];
    }
    __syncthreads();
    {
        const int nn = t >> 2, ks = (t & 3) * 16;
        bf16x8 v0, v1;
        #pragma unroll
        for (int j = 0; j < 8; ++j) v0[j] = (short)f2bf(Tl[ks + j][nn]);
        #pragma unroll
        for (int j = 0; j < 8; ++j) v1[j] = (short)f2bf(Tl[ks + 8 + j][nn]);
        unsigned short* dp = dst + (size_t)(n0 + nn) * Dc + k0 + ks;
        *(bf16x8*)dp       = v0;
        *(bf16x8*)(dp + 8) = v1;
    }
}

// ---------------------------------------------------------------------------
// K1: q/k projection GEMM, LDS-staged (coalesced global reads), double-buffered.
// Tile 128x128, BK=32, 512 thr = 8 waves, wave tile 64x32 (4x2 frags).
// ---------------------------------------------------------------------------
__global__ __launch_bounds__(512)
void qk_gemm(const unsigned short* __restrict__ hidb,
             const unsigned short* __restrict__ Wtq, const unsigned short* __restrict__ Wtk,
             const float* __restrict__ bq, const float* __restrict__ bk,
             unsigned short* __restrict__ qbuf, unsigned short* __restrict__ kbuf)
{
    __shared__ unsigned short As[2][128][40];
    __shared__ unsigned short Bs[2][128][40];

    const unsigned short* Wt = blockIdx.z ? Wtk : Wtq;
    const float* bi = blockIdx.z ? bk : bq;
    unsigned short* C = blockIdx.z ? kbuf : qbuf;
    const int m0 = blockIdx.x * 128, n0 = blockIdx.y * 128;
    const int t = threadIdx.x, lane = t & 63, w = t >> 6;
    const int lr = lane & 15, lg = lane >> 4;
    const int wmloc = (w >> 2) * 64, wnloc = (w & 3) * 32;

    const int srow = t >> 2, scol = (t & 3) * 8;
    const unsigned short* Ag = hidb + (size_t)(m0 + srow) * Dc + scol;
    const unsigned short* Bg = Wt   + (size_t)(n0 + srow) * Dc + scol;

    f32x4 acc[4][2] = {};
    bf16x8 ra = *(const bf16x8*)Ag;
    bf16x8 rb = *(const bf16x8*)Bg;

    for (int it = 0; it < 32; ++it) {
        const int buf = it & 1;
        *(bf16x8*)&As[buf][srow][scol] = ra;
        *(bf16x8*)&Bs[buf][srow][scol] = rb;
        __syncthreads();
        if (it < 31) {
            ra = *(const bf16x8*)(Ag + (it + 1) * 32);
            rb = *(const bf16x8*)(Bg + (it + 1) * 32);
        }
        bf16x8 a[4], bfr[2];
        #pragma unroll
        for (int mi = 0; mi < 4; ++mi)
            a[mi] = *(const bf16x8*)&As[buf][wmloc + mi * 16 + lr][lg * 8];
        #pragma unroll
        for (int ni = 0; ni < 2; ++ni)
            bfr[ni] = *(const bf16x8*)&Bs[buf][wnloc + ni * 16 + lr][lg * 8];
        #pragma unroll
        for (int mi = 0; mi < 4; ++mi)
            #pragma unroll
            for (int ni = 0; ni < 2; ++ni)
                acc[mi][ni] = __builtin_amdgcn_mfma_f32_16x16x32_bf16(a[mi], bfr[ni], acc[mi][ni], 0, 0, 0);
    }

    #pragma unroll
    for (int ni = 0; ni < 2; ++ni) {
        const int gc = n0 + wnloc + ni * 16 + lr;
        const float bv = bi[gc];
        #pragma unroll
        for (int mi = 0; mi < 4; ++mi)
            #pragma unroll
            for (int r = 0; r < 4; ++r) {
                const int row = m0 + wmloc + mi * 16 + lg * 4 + r;
                float v = fmaxf(acc[mi][ni][r] + bv, 0.0f);
                C[(size_t)row * NHc + gc] = f2bf(v);
            }
    }
}

// ---------------------------------------------------------------------------
// K2 (fused): scores -> softmax -> att write -> PV -> residual, QB=16 q-rows
// per block, 512 thr = 8 waves.  Round-9 structure with: (1) full-line
// coalesced K staging (8 rows/wave-instr), (2) P3 stages 2 V-tiles per
// barrier (halved latency exposures), (3) s_setprio around MFMA clusters.
// 67 KB LDS -> 2 blocks/CU.  Causal: valid iff s < q; row 0 -> uniform 1/1024.
// ---------------------------------------------------------------------------
__global__ __launch_bounds__(512)
void attn_fused(const unsigned short* __restrict__ qbuf,
                const unsigned short* __restrict__ kbuf,
                const unsigned short* __restrict__ hidb,
                const float* __restrict__ res,
                float* __restrict__ att, float* __restrict__ outp,
                unsigned short* __restrict__ hidnext)
{
    __shared__ unsigned short Sb[QB][1040];     // bf16 score/P strip (33.3 KB)
    __shared__ unsigned short KV[2][64][132];   // K/V staging (33.8 KB)

    const int id = blockIdx.x;
    const int kh = id & 7, qt = (id >> 3) & 63, b = id >> 9;
    const int q0 = qt * QB;
    const int t = threadIdx.x, lane = t & 63, w = t >> 6;
    const int lr = lane & 15, lg = lane >> 4;

    bf16x8 aq[2];
    #pragma unroll
    for (int ks = 0; ks < 2; ++ks)
        aq[ks] = *(const bf16x8*)(qbuf + (size_t)(b * Lc + q0 + lr) * NHc + kh * Hc + ks * 32 + lg * 8);

    const int ccount = (q0 + QB + 63) >> 6;   // 64-col chunks needed (1..16)

    // ---- P1: scores -> Sb (bf16).  2 K-chunks per barrier-pair; staging is
    //      full-line coalesced: 8 rows x 128B per wave-instruction. ----
    const int sh = t >> 8, rr = (t & 255) >> 3, cc = (t & 7) * 8;
    for (int cb = 0; cb < ccount; cb += 2) {
        const int cs = cb + sh;
        if (cs < ccount) {
            const unsigned short* kp = kbuf + (size_t)(b * Lc + cs * 64 + rr) * NHc + kh * Hc + cc;
            *(bf16x8*)&KV[sh][rr][cc]      = *(const bf16x8*)kp;
            *(bf16x8*)&KV[sh][rr + 32][cc] = *(const bf16x8*)(kp + (size_t)32 * NHc);
        }
        __syncthreads();
        const int c = cb + (w >> 2);
        if (c < ccount) {
            const int ni = w & 3;
            f32x4 acc = {};
            __builtin_amdgcn_s_setprio(1);
            #pragma unroll
            for (int ks = 0; ks < 2; ++ks) {
                bf16x8 bfr = *(const bf16x8*)&KV[w >> 2][ni * 16 + lr][ks * 32 + lg * 8];
                acc = __builtin_amdgcn_mfma_f32_16x16x32_bf16(aq[ks], bfr, acc, 0, 0, 0);
            }
            __builtin_amdgcn_s_setprio(0);
            #pragma unroll
            for (int r = 0; r < 4; ++r)
                Sb[lg * 4 + r][c * 64 + ni * 16 + lr] = f2bf(acc[r] * SCALE);
        }
        __syncthreads();
    }

    // ---- P2: softmax, 2 rows per wave.  fp32 att to global; bf16 P to Sb. ----
    #pragma unroll
    for (int i = 0; i < 2; ++i) {
        const int row = w * 2 + i, qrow = q0 + row;
        float* orow = att + ((size_t)(b * Kc + kh) * Lc + qrow) * Lc;
        if (qrow == 0) {
            const float u = 1.0f / 1024.0f;
            const short ub = (short)f2bf(u);
            bf16x8 pv8;
            #pragma unroll
            for (int j = 0; j < 8; ++j) pv8[j] = ub;
            #pragma unroll
            for (int tt = 0; tt < 2; ++tt) {
                const int col = lane * 8 + tt * 512;
                float4 o = { u, u, u, u };
                *(float4*)(orow + col) = o;
                *(float4*)(orow + col + 4) = o;
                *(bf16x8*)&Sb[row][col] = pv8;
            }
            continue;
        }
        float p[16];
        float mx = -3.0e38f;
        #pragma unroll
        for (int tt = 0; tt < 2; ++tt) {
            const int col = lane * 8 + tt * 512;
            bf16x8 v = *(const bf16x8*)&Sb[row][col];
            #pragma unroll
            for (int j = 0; j < 8; ++j) {
                const float f = bf2f((unsigned short)v[j]);
                p[tt * 8 + j] = f;
                if (col + j < qrow) mx = fmaxf(mx, f);
            }
        }
        #pragma unroll
        for (int off = 1; off < 64; off <<= 1) mx = fmaxf(mx, __shfl_xor(mx, off));
        float sum = 0.0f;
        #pragma unroll
        for (int tt = 0; tt < 2; ++tt)
            #pragma unroll
            for (int j = 0; j < 8; ++j) {
                const int col = lane * 8 + tt * 512 + j;
                const float e = (col < qrow) ? __expf(p[tt * 8 + j] - mx) : 0.0f;
                p[tt * 8 + j] = e; sum += e;
            }
        #pragma unroll
        for (int off = 1; off < 64; off <<= 1) sum += __shfl_xor(sum, off);
        const float inv = 1.0f / sum;
        #pragma unroll
        for (int tt = 0; tt < 2; ++tt) {
            const int col = lane * 8 + tt * 512;
            float4 o0 = { p[tt*8+0]*inv, p[tt*8+1]*inv, p[tt*8+2]*inv, p[tt*8+3]*inv };
            float4 o1 = { p[tt*8+4]*inv, p[tt*8+5]*inv, p[tt*8+6]*inv, p[tt*8+7]*inv };
            *(float4*)(orow + col) = o0;
            *(float4*)(orow + col + 4) = o1;
            bf16x8 pb;
            #pragma unroll
            for (int j = 0; j < 8; ++j) pb[j] = (short)f2bf(p[tt * 8 + j] * inv);
            *(bf16x8*)&Sb[row][col] = pb;
        }
    }
    __syncthreads();

    // ---- P3: PV (+residual).  2 V-tiles staged per barrier, full-line
    //      coalesced; fragments read from LDS (round-9 gather). ----
    const int stiles = (qt == 0) ? 16 : ccount;   // row 0 is a full uniform row
    f32x4 acc3 = {};
    const int dloc = w * 16 + lr, dcol = kh * 128 + dloc;
    const int vrow = t >> 3, vcol = (t & 7) * 8;
    const unsigned short* vb = hidb + (size_t)(b * Lc + vrow) * Dc + kh * 128 + vcol;
    for (int tp = 0; tp < stiles; tp += 2) {
        {
            const unsigned short* vp = vb + (size_t)tp * 64 * Dc;
            *(bf16x8*)&KV[0][vrow][vcol]      = *(const bf16x8*)vp;
            *(bf16x8*)&KV[0][vrow][vcol + 64] = *(const bf16x8*)(vp + 64);
            if (tp + 1 < stiles) {
                const unsigned short* vp1 = vp + (size_t)64 * Dc;
                *(bf16x8*)&KV[1][vrow][vcol]      = *(const bf16x8*)vp1;
                *(bf16x8*)&KV[1][vrow][vcol + 64] = *(const bf16x8*)(vp1 + 64);
            }
        }
        __syncthreads();
        __builtin_amdgcn_s_setprio(1);
        #pragma unroll
        for (int h = 0; h < 2; ++h) {
            if (tp + h < stiles) {
                #pragma unroll
                for (int ks = 0; ks < 2; ++ks) {
                    bf16x8 pa = *(const bf16x8*)&Sb[lr][(tp + h) * 64 + ks * 32 + lg * 8];
                    bf16x8 bb;
                    #pragma unroll
                    for (int j = 0; j < 8; ++j)
                        bb[j] = (short)KV[h][ks * 32 + lg * 8 + j][dloc];
                    acc3 = __builtin_amdgcn_mfma_f32_16x16x32_bf16(pa, bb, acc3, 0, 0, 0);
                }
            }
        }
        __builtin_amdgcn_s_setprio(0);
        __syncthreads();
    }

    #pragma unroll
    for (int r = 0; r < 4; ++r) {
        const size_t idx = (size_t)(b * Lc + q0 + lg * 4 + r) * Dc + dcol;
        const float v = res[idx] + acc3[r];
        outp[idx] = v;
        if (hidnext) hidnext[idx] = f2bf(v);
    }
}

// ---------------------------------------------------------------------------
extern "C" void kernel_launch(void* const* d_in, const int* in_sizes, int n_in,
                              void* d_out, int out_size, void* d_ws, size_t ws_size,
                              hipStream_t stream)
{
    const float* x  = (const float*)d_in[0];
    const float* Wq = (const float*)d_in[1];
    const float* bq = (const float*)d_in[2];
    const float* Wk = (const float*)d_in[3];
    const float* bk = (const float*)d_in[4];
    float* out = (float*)d_out;

    unsigned short* hidbA = (unsigned short*)d_ws;             // [4096][1024] bf16 (8 MB)
    unsigned short* hidbB = hidbA + (size_t)Bc * Lc * Dc;      // [4096][1024] bf16 (8 MB)
    unsigned short* qb    = hidbB + (size_t)Bc * Lc * Dc;      // [4096][512]  bf16 (4 MB)
    unsigned short* kb    = qb    + (size_t)Bc * Lc * NHc;     // [4096][512]  bf16 (4 MB)

    const int nhid = Bc * Lc * Dc;   // 4194304

    cast_bf16<<<nhid / 8 / 256, 256, 0, stream>>>(x, hidbA, nhid);
    wtrans<<<dim3(16, 8, 4), 256, 0, stream>>>(Wq, Wk, out);

    for (int l = 0; l < 2; ++l) {
        float* attL = out + (size_t)l * (GSZ / 2);
        float* outL = out + GSZ + (size_t)l * OSZ;
        const float* resL = l ? (out + GSZ) : x;
        const unsigned short* hidL = l ? hidbB : hidbA;
        const unsigned short* WtL = (const unsigned short*)attL;

        qk_gemm<<<dim3(32, 4, 2), 512, 0, stream>>>(
            hidL, WtL, WtL + (size_t)NHc * Dc, bq + l * NHc, bk + l * NHc, qb, kb);

        attn_fused<<<Bc * 64 * Kc, 512, 0, stream>>>(
            qb, kb, hidL, resL, attL, outL, l == 0 ? hidbB : (unsigned short*)nullptr);
    }
}